// Round 1
// baseline (7937.315 us; speedup 1.0000x reference)
//
#include <hip/hip_runtime.h>
#include <math.h>

namespace {

constexpr int BB = 8;
constexpr int LL = 768;
constexpr int DD = 512;
constexpr float NEGF = -1e9f;

__device__ __forceinline__ float softplus_f(float x) {
  // matches jax.nn.softplus = logaddexp(x, 0)
  return x > 0.f ? x + log1pf(expf(-x)) : log1pf(expf(x));
}
__device__ __forceinline__ float logsigmoid_f(float x) {
  // matches jax.nn.log_sigmoid = -softplus(-x)
  return x > 0.f ? -log1pf(expf(-x)) : x - log1pf(expf(x));
}

// -------- Kernel A: out[r][c] = sum_d X[r][d] * W[c][d] + bias[c] --------
// X: (BB*LL, DD) row-major, W: (DD, DD) row-major (we need X @ W^T).
__global__ __launch_bounds__(256) void linear_kernel(
    const float* __restrict__ hx, const float* __restrict__ hy,
    const float* __restrict__ Wm, const float* __restrict__ bm,
    const float* __restrict__ Wg, const float* __restrict__ bg,
    float* __restrict__ zx, float* __restrict__ zy,
    float* __restrict__ gx, float* __restrict__ gy) {
  constexpr int BK = 16;
  __shared__ float Xs[BK][64 + 1];
  __shared__ float Ws[BK][64 + 1];

  const int which = blockIdx.z;  // 0:zx=hx*Wm 1:zy=hy*Wm 2:gx=hx*Wg 3:gy=hy*Wg
  const float* Xin  = (which & 1) ? hy : hx;
  const float* W    = (which >= 2) ? Wg : Wm;
  const float* bias = (which >= 2) ? bg : bm;
  float* out = (which == 0) ? zx : (which == 1) ? zy : (which == 2) ? gx : gy;

  const int row0 = blockIdx.y * 64;
  const int col0 = blockIdx.x * 64;
  const int t  = threadIdx.x;
  const int tx = t & 15;       // 0..15 (cols)
  const int ty = t >> 4;       // 0..15 (rows)
  const int lrow = t >> 2;     // 0..63 loader row
  const int lseg = (t & 3) * 4;

  float acc[4][4] = {};
  for (int k0 = 0; k0 < DD; k0 += BK) {
    const float4 xv = *(const float4*)(Xin + (size_t)(row0 + lrow) * DD + k0 + lseg);
    const float4 wv = *(const float4*)(W   + (size_t)(col0 + lrow) * DD + k0 + lseg);
    Xs[lseg + 0][lrow] = xv.x; Xs[lseg + 1][lrow] = xv.y;
    Xs[lseg + 2][lrow] = xv.z; Xs[lseg + 3][lrow] = xv.w;
    Ws[lseg + 0][lrow] = wv.x; Ws[lseg + 1][lrow] = wv.y;
    Ws[lseg + 2][lrow] = wv.z; Ws[lseg + 3][lrow] = wv.w;
    __syncthreads();
#pragma unroll
    for (int kk = 0; kk < BK; ++kk) {
      float xr[4], wr[4];
#pragma unroll
      for (int a = 0; a < 4; ++a) xr[a] = Xs[kk][ty * 4 + a];
#pragma unroll
      for (int b = 0; b < 4; ++b) wr[b] = Ws[kk][tx * 4 + b];
#pragma unroll
      for (int a = 0; a < 4; ++a)
#pragma unroll
        for (int b = 0; b < 4; ++b) acc[a][b] += xr[a] * wr[b];
    }
    __syncthreads();
  }
#pragma unroll
  for (int a = 0; a < 4; ++a) {
    const int r = row0 + ty * 4 + a;
#pragma unroll
    for (int b2 = 0; b2 < 4; ++b2) {
      const int c = col0 + tx * 4 + b2;
      out[(size_t)r * DD + c] = acc[a][b2] + bias[c];
    }
  }
}

// -------- Kernel B: theta/A batched logits: out[i][j] = f(dot(X[i], Y[j])) --------
__global__ __launch_bounds__(256) void logits_kernel(
    const float* __restrict__ zx, const float* __restrict__ zy,
    const float* __restrict__ gx, const float* __restrict__ gy,
    float* __restrict__ theta, float* __restrict__ Aout) {
  constexpr int BK = 16;
  __shared__ float Xs[BK][64 + 1];
  __shared__ float Ys[BK][64 + 1];

  const int bz = blockIdx.z;   // b*2 + w
  const int b = bz >> 1, w = bz & 1;
  const float* X = (w ? gx : zx) + (size_t)b * LL * DD;
  const float* Y = (w ? gy : zy) + (size_t)b * LL * DD;
  float* out = (w ? Aout : theta) + (size_t)b * LL * LL;

  const int row0 = blockIdx.y * 64;
  const int col0 = blockIdx.x * 64;
  const int t  = threadIdx.x;
  const int tx = t & 15;
  const int ty = t >> 4;
  const int lrow = t >> 2;
  const int lseg = (t & 3) * 4;

  float acc[4][4] = {};
  for (int k0 = 0; k0 < DD; k0 += BK) {
    const float4 xv = *(const float4*)(X + (size_t)(row0 + lrow) * DD + k0 + lseg);
    const float4 yv = *(const float4*)(Y + (size_t)(col0 + lrow) * DD + k0 + lseg);
    Xs[lseg + 0][lrow] = xv.x; Xs[lseg + 1][lrow] = xv.y;
    Xs[lseg + 2][lrow] = xv.z; Xs[lseg + 3][lrow] = xv.w;
    Ys[lseg + 0][lrow] = yv.x; Ys[lseg + 1][lrow] = yv.y;
    Ys[lseg + 2][lrow] = yv.z; Ys[lseg + 3][lrow] = yv.w;
    __syncthreads();
#pragma unroll
    for (int kk = 0; kk < BK; ++kk) {
      float xr[4], yr[4];
#pragma unroll
      for (int a = 0; a < 4; ++a) xr[a] = Xs[kk][ty * 4 + a];
#pragma unroll
      for (int b2 = 0; b2 < 4; ++b2) yr[b2] = Ys[kk][tx * 4 + b2];
#pragma unroll
      for (int a = 0; a < 4; ++a)
#pragma unroll
        for (int b2 = 0; b2 < 4; ++b2) acc[a][b2] += xr[a] * yr[b2];
    }
    __syncthreads();
  }
#pragma unroll
  for (int a = 0; a < 4; ++a) {
    const int r = row0 + ty * 4 + a;
#pragma unroll
    for (int b2 = 0; b2 < 4; ++b2) {
      const int c = col0 + tx * 4 + b2;
      const float v = acc[a][b2];
      out[(size_t)r * LL + c] = w ? logsigmoid_f(v) : softplus_f(v);
    }
  }
}

// -------- NW forward: V[i,j] = theta[i-1,j-1] + LSE(V[i-1,j-1], A+V[i,j-1], A+V[i-1,j]) --------
__global__ __launch_bounds__(LL) void nw_forward(
    const float* __restrict__ theta, const float* __restrict__ A,
    float* __restrict__ V) {
  const int b = blockIdx.x;
  const float* th = theta + (size_t)b * LL * LL;
  const float* a  = A + (size_t)b * LL * LL;
  float* Vb = V + (size_t)b * (LL + 1) * (LL + 1);
  const int t = threadIdx.x;

  // borders
  for (int idx = t; idx <= LL; idx += blockDim.x) {
    Vb[idx] = (idx == 0) ? 0.f : NEGF;                    // row 0
    if (idx > 0) Vb[(size_t)idx * (LL + 1)] = NEGF;       // col 0
  }
  __syncthreads();

  const int i = t + 1;  // 1..LL
  for (int k = 2; k <= 2 * LL; ++k) {
    const int j = k - i;
    if (j >= 1 && j <= LL) {
      const float Vd = Vb[(size_t)(i - 1) * (LL + 1) + (j - 1)];
      const float Vl = Vb[(size_t)i * (LL + 1) + (j - 1)];
      const float Vu = Vb[(size_t)(i - 1) * (LL + 1) + j];
      const float aa = a[(size_t)(i - 1) * LL + (j - 1)];
      const float l = aa + Vl;
      const float u = aa + Vu;
      const float m = fmaxf(Vd, fmaxf(l, u));
      const float lse = m + logf(expf(Vd - m) + expf(l - m) + expf(u - m));
      Vb[(size_t)i * (LL + 1) + j] = th[(size_t)(i - 1) * LL + (j - 1)] + lse;
    }
    __syncthreads();
  }
}

// -------- NW backward: E[i,j] = sum of weighted E from (i+1,j+1),(i,j+1),(i+1,j) --------
// E stored directly in aln slice: E[i,j] <-> aln[b][i-1][j-1].
__global__ __launch_bounds__(LL) void nw_backward(
    const float* __restrict__ theta, const float* __restrict__ A,
    const float* __restrict__ V, float* __restrict__ aln) {
  const int b = blockIdx.x;
  const float* th = theta + (size_t)b * LL * LL;
  const float* a  = A + (size_t)b * LL * LL;
  const float* Vb = V + (size_t)b * (LL + 1) * (LL + 1);
  float* E = aln + (size_t)b * LL * LL;   // E[i][j] = E[(i-1)*LL + (j-1)]
  const int t = threadIdx.x;
  const int i = t + 1;  // 1..LL

  for (int k = 2 * LL; k >= 2; --k) {
    const int j = k - i;
    if (j >= 1 && j <= LL) {
      float e;
      if (i == LL && j == LL) {
        e = 1.f;
      } else {
        const float Vij = Vb[(size_t)i * (LL + 1) + j];
        e = 0.f;
        if (i < LL && j < LL) {
          // diag weight at cell (i+1, j+1): theta0[i][j]
          e += E[(size_t)i * LL + j] *
               expf(Vij - (Vb[(size_t)(i + 1) * (LL + 1) + (j + 1)] - th[(size_t)i * LL + j]));
        }
        if (j < LL) {
          // left weight at cell (i, j+1): A0[i-1][j], theta0[i-1][j]
          e += E[(size_t)(i - 1) * LL + j] *
               expf(a[(size_t)(i - 1) * LL + j] + Vij -
                    (Vb[(size_t)i * (LL + 1) + (j + 1)] - th[(size_t)(i - 1) * LL + j]));
        }
        if (i < LL) {
          // up weight at cell (i+1, j): A0[i][j-1], theta0[i][j-1]
          e += E[(size_t)i * LL + (j - 1)] *
               expf(a[(size_t)i * LL + (j - 1)] + Vij -
                    (Vb[(size_t)(i + 1) * (LL + 1) + j] - th[(size_t)i * LL + (j - 1)]));
        }
      }
      E[(size_t)(i - 1) * LL + (j - 1)] = e;
    }
    __syncthreads();
  }
}

}  // namespace

extern "C" void kernel_launch(void* const* d_in, const int* in_sizes, int n_in,
                              void* d_out, int out_size, void* d_ws, size_t ws_size,
                              hipStream_t stream) {
  const float* hx = (const float*)d_in[0];
  const float* hy = (const float*)d_in[1];
  const float* Wm = (const float*)d_in[2];
  const float* bm = (const float*)d_in[3];
  const float* Wg = (const float*)d_in[4];
  const float* bg = (const float*)d_in[5];

  float* aln   = (float*)d_out;
  float* theta = aln + (size_t)BB * LL * LL;
  float* A     = theta + (size_t)BB * LL * LL;

  float* zx = (float*)d_ws;
  float* zy = zx + (size_t)BB * LL * DD;
  float* gx = zy + (size_t)BB * LL * DD;
  float* gy = gx + (size_t)BB * LL * DD;
  float* V  = gy + (size_t)BB * LL * DD;  // BB*(LL+1)*(LL+1) floats

  linear_kernel<<<dim3(DD / 64, (BB * LL) / 64, 4), 256, 0, stream>>>(
      hx, hy, Wm, bm, Wg, bg, zx, zy, gx, gy);
  logits_kernel<<<dim3(LL / 64, LL / 64, BB * 2), 256, 0, stream>>>(
      zx, zy, gx, gy, theta, A);
  nw_forward<<<BB, LL, 0, stream>>>(theta, A, V);
  nw_backward<<<BB, LL, 0, stream>>>(theta, A, V, aln);
}

// Round 2
// 3088.983 us; speedup vs baseline: 2.5696x; 2.5696x over previous
//
#include <hip/hip_runtime.h>
#include <math.h>

namespace {

constexpr int BB = 8;
constexpr int LL = 768;
constexpr int DD = 512;
constexpr int L2E = LL * LL;
constexpr float NEGF = -1e9f;
constexpr int KMAX = 2 * LL;  // 1536

__device__ __forceinline__ float softplus_f(float x) {
  return x > 0.f ? x + log1pf(expf(-x)) : log1pf(expf(x));
}
__device__ __forceinline__ float logsigmoid_f(float x) {
  return x > 0.f ? -log1pf(expf(-x)) : x - log1pf(expf(x));
}

// diagonal-compact offset/len for an LLxLL matrix, diag s = r + c in [0, 2L-2]
__device__ __forceinline__ int doff(int s) {
  return (s <= LL - 1) ? (s * (s + 1)) / 2
                       : LL * LL - ((2 * LL - 1 - s) * (2 * LL - s)) / 2;
}
__device__ __forceinline__ int dlen(int s) { return LL - abs(s - (LL - 1)); }

// -------- Kernel A: out[r][c] = sum_d X[r][d] * W[c][d] + bias[c] --------
__global__ __launch_bounds__(256) void linear_kernel(
    const float* __restrict__ hx, const float* __restrict__ hy,
    const float* __restrict__ Wm, const float* __restrict__ bm,
    const float* __restrict__ Wg, const float* __restrict__ bg,
    float* __restrict__ zx, float* __restrict__ zy,
    float* __restrict__ gx, float* __restrict__ gy) {
  constexpr int BK = 16;
  __shared__ float Xs[BK][64 + 1];
  __shared__ float Ws[BK][64 + 1];

  const int which = blockIdx.z;
  const float* Xin  = (which & 1) ? hy : hx;
  const float* W    = (which >= 2) ? Wg : Wm;
  const float* bias = (which >= 2) ? bg : bm;
  float* out = (which == 0) ? zx : (which == 1) ? zy : (which == 2) ? gx : gy;

  const int row0 = blockIdx.y * 64;
  const int col0 = blockIdx.x * 64;
  const int t  = threadIdx.x;
  const int tx = t & 15;
  const int ty = t >> 4;
  const int lrow = t >> 2;
  const int lseg = (t & 3) * 4;

  float acc[4][4] = {};
  for (int k0 = 0; k0 < DD; k0 += BK) {
    const float4 xv = *(const float4*)(Xin + (size_t)(row0 + lrow) * DD + k0 + lseg);
    const float4 wv = *(const float4*)(W   + (size_t)(col0 + lrow) * DD + k0 + lseg);
    Xs[lseg + 0][lrow] = xv.x; Xs[lseg + 1][lrow] = xv.y;
    Xs[lseg + 2][lrow] = xv.z; Xs[lseg + 3][lrow] = xv.w;
    Ws[lseg + 0][lrow] = wv.x; Ws[lseg + 1][lrow] = wv.y;
    Ws[lseg + 2][lrow] = wv.z; Ws[lseg + 3][lrow] = wv.w;
    __syncthreads();
#pragma unroll
    for (int kk = 0; kk < BK; ++kk) {
      float xr[4], wr[4];
#pragma unroll
      for (int a = 0; a < 4; ++a) xr[a] = Xs[kk][ty * 4 + a];
#pragma unroll
      for (int b = 0; b < 4; ++b) wr[b] = Ws[kk][tx * 4 + b];
#pragma unroll
      for (int a = 0; a < 4; ++a)
#pragma unroll
        for (int b = 0; b < 4; ++b) acc[a][b] += xr[a] * wr[b];
    }
    __syncthreads();
  }
#pragma unroll
  for (int a = 0; a < 4; ++a) {
    const int r = row0 + ty * 4 + a;
#pragma unroll
    for (int b2 = 0; b2 < 4; ++b2) {
      const int c = col0 + tx * 4 + b2;
      out[(size_t)r * DD + c] = acc[a][b2] + bias[c];
    }
  }
}

// -------- Kernel B: theta/A batched logits --------
__global__ __launch_bounds__(256) void logits_kernel(
    const float* __restrict__ zx, const float* __restrict__ zy,
    const float* __restrict__ gx, const float* __restrict__ gy,
    float* __restrict__ theta, float* __restrict__ Aout) {
  constexpr int BK = 16;
  __shared__ float Xs[BK][64 + 1];
  __shared__ float Ys[BK][64 + 1];

  const int bz = blockIdx.z;
  const int b = bz >> 1, w = bz & 1;
  const float* X = (w ? gx : zx) + (size_t)b * LL * DD;
  const float* Y = (w ? gy : zy) + (size_t)b * LL * DD;
  float* out = (w ? Aout : theta) + (size_t)b * L2E;

  const int row0 = blockIdx.y * 64;
  const int col0 = blockIdx.x * 64;
  const int t  = threadIdx.x;
  const int tx = t & 15;
  const int ty = t >> 4;
  const int lrow = t >> 2;
  const int lseg = (t & 3) * 4;

  float acc[4][4] = {};
  for (int k0 = 0; k0 < DD; k0 += BK) {
    const float4 xv = *(const float4*)(X + (size_t)(row0 + lrow) * DD + k0 + lseg);
    const float4 yv = *(const float4*)(Y + (size_t)(col0 + lrow) * DD + k0 + lseg);
    Xs[lseg + 0][lrow] = xv.x; Xs[lseg + 1][lrow] = xv.y;
    Xs[lseg + 2][lrow] = xv.z; Xs[lseg + 3][lrow] = xv.w;
    Ys[lseg + 0][lrow] = yv.x; Ys[lseg + 1][lrow] = yv.y;
    Ys[lseg + 2][lrow] = yv.z; Ys[lseg + 3][lrow] = yv.w;
    __syncthreads();
#pragma unroll
    for (int kk = 0; kk < BK; ++kk) {
      float xr[4], yr[4];
#pragma unroll
      for (int a = 0; a < 4; ++a) xr[a] = Xs[kk][ty * 4 + a];
#pragma unroll
      for (int b2 = 0; b2 < 4; ++b2) yr[b2] = Ys[kk][tx * 4 + b2];
#pragma unroll
      for (int a = 0; a < 4; ++a)
#pragma unroll
        for (int b2 = 0; b2 < 4; ++b2) acc[a][b2] += xr[a] * yr[b2];
    }
    __syncthreads();
  }
#pragma unroll
  for (int a = 0; a < 4; ++a) {
    const int r = row0 + ty * 4 + a;
#pragma unroll
    for (int b2 = 0; b2 < 4; ++b2) {
      const int c = col0 + tx * 4 + b2;
      const float v = acc[a][b2];
      out[(size_t)r * LL + c] = w ? logsigmoid_f(v) : softplus_f(v);
    }
  }
}

// -------- Fused NW forward + backward, one block per batch --------
// LDS layout (floats): thB[768*17], aB[768*17], Vr[4][772], Er[3][772]
__global__ __launch_bounds__(768, 1) void nw_fused(
    const float* __restrict__ theta, const float* __restrict__ A,
    float* __restrict__ Vd, float* __restrict__ Ed) {
  extern __shared__ float sm[];
  float* thB = sm;              // 13056
  float* aB  = thB + 768 * 17;  // 13056
  float* Vr  = aB + 768 * 17;   // 4*772
  float* Er  = Vr + 4 * 772;    // 3*772
  const int b = blockIdx.x;
  const float* th = theta + (size_t)b * L2E;
  const float* a  = A + (size_t)b * L2E;
  float* Vo = Vd + (size_t)b * L2E;
  float* Eo = Ed + (size_t)b * L2E;
  const int t = threadIdx.x;
  const int i = t + 1;  // 1..768

  // ================= forward =================
  // ring slots 0..2 used; diag0 -> slot 0 (V(0,0)=0 else NEG), diag1 -> slot 1 (all NEG)
  Vr[0 * 772 + t] = NEGF;
  Vr[1 * 772 + t] = NEGF;
  Vr[2 * 772 + t] = NEGF;
  if (t == 0) {
    Vr[0 * 772 + 768] = NEGF; Vr[1 * 772 + 768] = NEGF; Vr[2 * 772 + 768] = NEGF;
    Vr[0 * 772 + 0] = 0.f;
  }

  float vcarry = 0.f; int vcaddr = -1;
  for (int k0 = 2; k0 <= KMAX; k0 += 16) {
    const int kend = min(KMAX, k0 + 15);
    // band: per row, cols c0(row) = k0-2-row .. +15
    for (int p = 0; p < 16; ++p) {
      const int row = p * 48 + (t >> 4);
      const int cc = t & 15;
      const int c = k0 - 2 - row + cc;
      const bool ok = (c >= 0) && (c < LL);
      thB[row * 17 + cc] = ok ? th[(size_t)row * LL + c] : 0.f;
      aB[row * 17 + cc]  = ok ? a[(size_t)row * LL + c] : 0.f;
    }
    __syncthreads();
    for (int k = k0; k <= kend; ++k) {
      if (vcaddr >= 0) Vo[vcaddr] = vcarry;  // delayed store (one step old)
      vcaddr = -1;
      const int j = k - i;
      float v = NEGF;
      if (j >= 1 && j <= LL) {
        const int cc = k - k0;
        const float Vdg = Vr[((k - 2) % 3) * 772 + (i - 1)];
        const float Vl  = Vr[((k - 1) % 3) * 772 + i];
        const float Vu  = Vr[((k - 1) % 3) * 772 + (i - 1)];
        const float aa  = aB[t * 17 + cc];
        const float l = aa + Vl, u = aa + Vu;
        const float m = fmaxf(Vdg, fmaxf(l, u));
        const float lse = m + __logf(__expf(Vdg - m) + __expf(l - m) + __expf(u - m));
        v = thB[t * 17 + cc] + lse;
        const int s = k - 2;
        vcarry = v;
        vcaddr = doff(s) + t - max(0, s - (LL - 1));
      }
      Vr[(k % 3) * 772 + i] = v;
      if (t == 0) Vr[(k % 3) * 772 + 0] = NEGF;
      __syncthreads();
    }
  }
  if (vcaddr >= 0) Vo[vcaddr] = vcarry;
  __syncthreads();  // drain V stores before backward reads them

  // ================= backward =================
  // prologue: diag 1536 -> Vr slot (1536%4)=0; pending register = diag 1535
  {
    const int s6 = KMAX - 2;  // 1534, len 1
    if (t < dlen(s6))
      Vr[(KMAX % 4) * 772 + (t + 1 + max(0, s6 - (LL - 1)))] = Vo[doff(s6) + t];
  }
  float vpend = 0.f;
  {
    const int s5 = KMAX - 3;  // 1533, len 2
    if (t < dlen(s5)) vpend = Vo[doff(s5) + t];
  }
  float ecarry = 0.f; int ecaddr = -1;
  for (int khi = KMAX; khi >= 2; khi -= 15) {
    const int klo = max(2, khi - 14);
    // band: per row, cols c0(row) = khi-15-row .. +15 (covers both k-row and k-1-row roles)
    for (int p = 0; p < 16; ++p) {
      const int row = p * 48 + (t >> 4);
      const int cc = t & 15;
      const int c = khi - 15 - row + cc;
      const bool ok = (c >= 0) && (c < LL);
      thB[row * 17 + cc] = ok ? th[(size_t)row * LL + c] : 0.f;
      aB[row * 17 + cc]  = ok ? a[(size_t)row * LL + c] : 0.f;
    }
    __syncthreads();
    for (int k = khi; k >= klo; --k) {
      if (ecaddr >= 0) Eo[ecaddr] = ecarry;  // delayed store
      ecaddr = -1;
      // publish pending V diag (k-1) to ring slot (k-1)%4
      if (k - 1 >= 2) {
        const int sp = k - 3;
        if (t < dlen(sp))
          Vr[((k - 1) % 4) * 772 + (t + 1 + max(0, sp - (LL - 1)))] = vpend;
      }
      // issue load of V diag (k-2) into register (consumed next step)
      float vnew = 0.f;
      if (k - 2 >= 2) {
        const int sn = k - 4;
        if (t < dlen(sn)) vnew = Vo[doff(sn) + t];
      }
      const int j = k - i;
      if (j >= 1 && j <= LL) {
        float e;
        if (k == KMAX) {
          e = 1.f;  // cell (L, L)
        } else {
          const float Vij = Vr[(k % 4) * 772 + i];
          const int cc1 = k - khi + 15;   // role: c = k - row
          const int cc23 = k - khi + 14;  // role: c = k-1 - row
          e = 0.f;
          if (i < LL && j < LL)
            e += Er[((k + 2) % 3) * 772 + (i + 1)] *
                 __expf(Vij - Vr[((k + 2) % 4) * 772 + (i + 1)] + thB[i * 17 + cc1]);
          if (j < LL)
            e += Er[((k + 1) % 3) * 772 + i] *
                 __expf(aB[t * 17 + cc23] + Vij - Vr[((k + 1) % 4) * 772 + i] +
                        thB[t * 17 + cc23]);
          if (i < LL)
            e += Er[((k + 1) % 3) * 772 + (i + 1)] *
                 __expf(aB[i * 17 + cc23] + Vij - Vr[((k + 1) % 4) * 772 + (i + 1)] +
                        thB[i * 17 + cc23]);
        }
        Er[(k % 3) * 772 + i] = e;
        const int s = k - 2;
        ecarry = e;
        ecaddr = doff(s) + t - max(0, s - (LL - 1));
      }
      vpend = vnew;
      __syncthreads();
    }
  }
  if (ecaddr >= 0) Eo[ecaddr] = ecarry;
}

// -------- diag-compact -> row-major (aln) --------
__global__ __launch_bounds__(256) void diag2row(
    const float* __restrict__ Ed, float* __restrict__ aln) {
  __shared__ float tile[64 * 66];
  const int b = blockIdx.z;
  const int r0 = blockIdx.y * 64;
  const int c0 = blockIdx.x * 64;
  const float* E = Ed + (size_t)b * L2E;
  float* out = aln + (size_t)b * L2E;
  const int t = threadIdx.x;
  const int lane = t & 63;
  const int grp = t >> 6;  // 0..3
  for (int si = grp; si < 127; si += 4) {
    const int s = r0 + c0 + si;
    const int rlo = max(r0, s - c0 - 63);
    const int rhi = min(r0 + 63, s - c0);
    const int r = rlo + lane;
    if (r <= rhi) {
      tile[(r - r0) * 66 + (s - r - c0)] = E[doff(s) + r - max(0, s - (LL - 1))];
    }
  }
  __syncthreads();
  for (int it = 0; it < 16; ++it) {
    const int rr = it * 4 + grp;
    out[(size_t)(r0 + rr) * LL + c0 + lane] = tile[rr * 66 + lane];
  }
}

}  // namespace

extern "C" void kernel_launch(void* const* d_in, const int* in_sizes, int n_in,
                              void* d_out, int out_size, void* d_ws, size_t ws_size,
                              hipStream_t stream) {
  const float* hx = (const float*)d_in[0];
  const float* hy = (const float*)d_in[1];
  const float* Wm = (const float*)d_in[2];
  const float* bm = (const float*)d_in[3];
  const float* Wg = (const float*)d_in[4];
  const float* bg = (const float*)d_in[5];

  float* aln   = (float*)d_out;
  float* theta = aln + (size_t)BB * L2E;
  float* A     = theta + (size_t)BB * L2E;

  // phase 1 workspace (dead after logits): zx, zy, gx, gy
  float* zx = (float*)d_ws;
  float* zy = zx + (size_t)BB * LL * DD;
  float* gx = zy + (size_t)BB * LL * DD;
  float* gy = gx + (size_t)BB * LL * DD;
  // phase 2 workspace (reuses the same region): Vd, Ed (diag-compact)
  float* Vd = (float*)d_ws;
  float* Ed = Vd + (size_t)BB * L2E;

  linear_kernel<<<dim3(DD / 64, (BB * LL) / 64, 4), 256, 0, stream>>>(
      hx, hy, Wm, bm, Wg, bg, zx, zy, gx, gy);
  logits_kernel<<<dim3(LL / 64, LL / 64, BB * 2), 256, 0, stream>>>(
      zx, zy, gx, gy, theta, A);

  const size_t SH = (size_t)(2 * 768 * 17 + 7 * 772) * sizeof(float);  // 126,064 B
  nw_fused<<<dim3(BB), 768, SH, stream>>>(theta, A, Vd, Ed);

  diag2row<<<dim3(LL / 64, LL / 64, BB), 256, 0, stream>>>(Ed, aln);
}

// Round 3
// 2949.366 us; speedup vs baseline: 2.6912x; 1.0473x over previous
//
#include <hip/hip_runtime.h>
#include <math.h>

namespace {

constexpr int BB = 8;
constexpr int LL = 768;
constexpr int DD = 512;
constexpr int L2E = LL * LL;
constexpr float NEGF = -1e9f;

__device__ __forceinline__ float softplus_f(float x) {
  return x > 0.f ? x + log1pf(expf(-x)) : log1pf(expf(x));
}
__device__ __forceinline__ float logsigmoid_f(float x) {
  return x > 0.f ? -log1pf(expf(-x)) : x - log1pf(expf(x));
}

__device__ __forceinline__ float sel4(float4 q, int c) {
  const float r01 = (c & 1) ? q.y : q.x;
  const float r23 = (c & 1) ? q.w : q.z;
  return (c & 2) ? r23 : r01;
}
__device__ __forceinline__ void ins4(float4& q, int c, float v) {
  if (c == 0) q.x = v;
  else if (c == 1) q.y = v;
  else if (c == 2) q.z = v;
  else q.w = v;
}

// -------- Kernel A: out[r][c] = sum_d X[r][d] * W[c][d] + bias[c] --------
__global__ __launch_bounds__(256) void linear_kernel(
    const float* __restrict__ hx, const float* __restrict__ hy,
    const float* __restrict__ Wm, const float* __restrict__ bm,
    const float* __restrict__ Wg, const float* __restrict__ bg,
    float* __restrict__ zx, float* __restrict__ zy,
    float* __restrict__ gx, float* __restrict__ gy) {
  constexpr int BK = 16;
  __shared__ float Xs[BK][64 + 1];
  __shared__ float Ws[BK][64 + 1];

  const int which = blockIdx.z;
  const float* Xin  = (which & 1) ? hy : hx;
  const float* W    = (which >= 2) ? Wg : Wm;
  const float* bias = (which >= 2) ? bg : bm;
  float* out = (which == 0) ? zx : (which == 1) ? zy : (which == 2) ? gx : gy;

  const int row0 = blockIdx.y * 64;
  const int col0 = blockIdx.x * 64;
  const int t  = threadIdx.x;
  const int tx = t & 15;
  const int ty = t >> 4;
  const int lrow = t >> 2;
  const int lseg = (t & 3) * 4;

  float acc[4][4] = {};
  for (int k0 = 0; k0 < DD; k0 += BK) {
    const float4 xv = *(const float4*)(Xin + (size_t)(row0 + lrow) * DD + k0 + lseg);
    const float4 wv = *(const float4*)(W   + (size_t)(col0 + lrow) * DD + k0 + lseg);
    Xs[lseg + 0][lrow] = xv.x; Xs[lseg + 1][lrow] = xv.y;
    Xs[lseg + 2][lrow] = xv.z; Xs[lseg + 3][lrow] = xv.w;
    Ws[lseg + 0][lrow] = wv.x; Ws[lseg + 1][lrow] = wv.y;
    Ws[lseg + 2][lrow] = wv.z; Ws[lseg + 3][lrow] = wv.w;
    __syncthreads();
#pragma unroll
    for (int kk = 0; kk < BK; ++kk) {
      float xr[4], wr[4];
#pragma unroll
      for (int a = 0; a < 4; ++a) xr[a] = Xs[kk][ty * 4 + a];
#pragma unroll
      for (int b = 0; b < 4; ++b) wr[b] = Ws[kk][tx * 4 + b];
#pragma unroll
      for (int a = 0; a < 4; ++a)
#pragma unroll
        for (int b = 0; b < 4; ++b) acc[a][b] += xr[a] * wr[b];
    }
    __syncthreads();
  }
#pragma unroll
  for (int a = 0; a < 4; ++a) {
    const int r = row0 + ty * 4 + a;
#pragma unroll
    for (int b2 = 0; b2 < 4; ++b2) {
      const int c = col0 + tx * 4 + b2;
      out[(size_t)r * DD + c] = acc[a][b2] + bias[c];
    }
  }
}

// -------- Kernel B: theta/A batched logits --------
__global__ __launch_bounds__(256) void logits_kernel(
    const float* __restrict__ zx, const float* __restrict__ zy,
    const float* __restrict__ gx, const float* __restrict__ gy,
    float* __restrict__ theta, float* __restrict__ Aout) {
  constexpr int BK = 16;
  __shared__ float Xs[BK][64 + 1];
  __shared__ float Ys[BK][64 + 1];

  const int bz = blockIdx.z;
  const int b = bz >> 1, w = bz & 1;
  const float* X = (w ? gx : zx) + (size_t)b * LL * DD;
  const float* Y = (w ? gy : zy) + (size_t)b * LL * DD;
  float* out = (w ? Aout : theta) + (size_t)b * L2E;

  const int row0 = blockIdx.y * 64;
  const int col0 = blockIdx.x * 64;
  const int t  = threadIdx.x;
  const int tx = t & 15;
  const int ty = t >> 4;
  const int lrow = t >> 2;
  const int lseg = (t & 3) * 4;

  float acc[4][4] = {};
  for (int k0 = 0; k0 < DD; k0 += BK) {
    const float4 xv = *(const float4*)(X + (size_t)(row0 + lrow) * DD + k0 + lseg);
    const float4 yv = *(const float4*)(Y + (size_t)(col0 + lrow) * DD + k0 + lseg);
    Xs[lseg + 0][lrow] = xv.x; Xs[lseg + 1][lrow] = xv.y;
    Xs[lseg + 2][lrow] = xv.z; Xs[lseg + 3][lrow] = xv.w;
    Ys[lseg + 0][lrow] = yv.x; Ys[lseg + 1][lrow] = yv.y;
    Ys[lseg + 2][lrow] = yv.z; Ys[lseg + 3][lrow] = yv.w;
    __syncthreads();
#pragma unroll
    for (int kk = 0; kk < BK; ++kk) {
      float xr[4], yr[4];
#pragma unroll
      for (int a = 0; a < 4; ++a) xr[a] = Xs[kk][ty * 4 + a];
#pragma unroll
      for (int b2 = 0; b2 < 4; ++b2) yr[b2] = Ys[kk][tx * 4 + b2];
#pragma unroll
      for (int a = 0; a < 4; ++a)
#pragma unroll
        for (int b2 = 0; b2 < 4; ++b2) acc[a][b2] += xr[a] * yr[b2];
    }
    __syncthreads();
  }
#pragma unroll
  for (int a = 0; a < 4; ++a) {
    const int r = row0 + ty * 4 + a;
#pragma unroll
    for (int b2 = 0; b2 < 4; ++b2) {
      const int c = col0 + tx * 4 + b2;
      const float v = acc[a][b2];
      out[(size_t)r * LL + c] = w ? logsigmoid_f(v) : softplus_f(v);
    }
  }
}

// -------- Fused NW fwd+bwd, barrier-free wave-pipelined systolic DP --------
// One block (768 threads = 12 waves) per batch. Lane = row i = tid+1.
// Intra-wave neighbor exchange: 3-deep LDS rings (program-order DS semantics).
// Cross-wave (rows 64w <-> 64w+1): full-history LDS boundary streams guarded by
// acquire/release progress counters; producers never wait -> deadlock-free.
__global__ __launch_bounds__(768, 1) void nw_fused(
    const float* __restrict__ theta, const float* __restrict__ A,
    float* __restrict__ Vst, float* __restrict__ aln) {
  extern __shared__ float sm[];
  int* Pf = (int*)sm;         // [12] forward progress (last k published)
  int* Pb = (int*)sm + 16;    // [12] backward progress (last k published, descending)
  float* U = sm + 32;
  // forward layout
  float* VrF = U;             // 3 * 772
  float* Bv  = U + 2320;      // 11 * 832
  // backward layout (reuses U after barrier)
  float* Vr2 = U;             // 3 * 772
  float* Er  = U + 2320;      // 3 * 772
  float* Bv2 = U + 4640;      // 11 * 768
  float* Be2 = U + 13088;     // 11 * 768

  const int b = blockIdx.x;
  const float* th = theta + (size_t)b * L2E;
  const float* a  = A + (size_t)b * L2E;
  float* Vb_ = Vst + (size_t)b * L2E;
  float* Eb_ = aln + (size_t)b * L2E;

  const int t = threadIdx.x;
  const int w = t >> 6, l = t & 63;
  const int i = t + 1;  // DP row, 1..768

  if (t < 12) { Pf[t] = 0; Pb[t] = 0x7fffffff; }
  __syncthreads();

  const float* thm = th + (size_t)(i - 1) * LL;  // theta row i-1 (0-based)
  const float* am  = a  + (size_t)(i - 1) * LL;  // A row i-1
  float* vrow = Vb_ + (size_t)(i - 1) * LL;      // V[i][j] at vrow[j-1]

  // ================= forward =================
  {
    float4 thc = *(const float4*)(thm);
    float4 thn = *(const float4*)(thm + 4);
    float4 ac  = *(const float4*)(am);
    float4 an  = *(const float4*)(am + 4);
    float hv1 = NEGF;       // own V[i][j-1]
    float4 vb = {};
    const int kb = 64 * w + 2, ke = 64 * w + 832;
    const int kbp = kb - 64;  // producer (w-1) k-base
    int sW = kb % 3;          // k%3
    int s1 = (kb + 2) % 3;    // (k-1)%3
    int s2 = (kb + 1) % 3;    // (k-2)%3
    for (int k = kb; k <= ke; ++k) {
      const int j = k - i;
      if (j >= 1 && j <= LL) {
        float Vu, Vd;
        if (l == 0) {
          if (w == 0) {
            Vu = NEGF;
            Vd = (j == 1) ? 0.f : NEGF;
          } else {
            while (__hip_atomic_load(&Pf[w - 1], __ATOMIC_ACQUIRE,
                                     __HIP_MEMORY_SCOPE_WORKGROUP) < k - 1) {}
            Vu = Bv[(w - 1) * 832 + (k - 1 - kbp)];
            Vd = (j == 1) ? NEGF : Bv[(w - 1) * 832 + (k - 2 - kbp)];
          }
        } else {
          Vu = VrF[s1 * 772 + (i - 1)];
          Vd = (j == 1) ? NEGF : VrF[s2 * 772 + (i - 1)];
        }
        const int m = j - 1, c = m & 3;
        const float thv = sel4(thc, c), av = sel4(ac, c);
        const float lft = av + hv1, up = av + Vu;
        const float mx = fmaxf(Vd, fmaxf(lft, up));
        const float v = thv + mx +
            __logf(__expf(Vd - mx) + __expf(lft - mx) + __expf(up - mx));
        hv1 = v;
        VrF[sW * 772 + i] = v;
        ins4(vb, c, v);
        if (c == 3) {
          *(float4*)(vrow + m - 3) = vb;
          thc = thn; ac = an;
          const int nb2 = (m + 5 < 764) ? (m + 5) : 764;
          thn = *(const float4*)(thm + nb2);
          an  = *(const float4*)(am + nb2);
        }
        if (l == 63 && w < 11) {
          Bv[w * 832 + (k - kb)] = v;
          __hip_atomic_store(&Pf[w], k, __ATOMIC_RELEASE,
                             __HIP_MEMORY_SCOPE_WORKGROUP);
        }
      }
      { const int tmp = s2; s2 = s1; s1 = sW; sW = tmp; }
      asm volatile("" ::: "memory");
    }
  }
  __syncthreads();

  // ================= backward =================
  {
    const float* thiR = th + (size_t)((i < LL) ? i : (LL - 1)) * LL;  // theta row i
    const float* aiR  = a  + (size_t)((i < LL) ? i : (LL - 1)) * LL;  // A row i
    float* erow = Eb_ + (size_t)(i - 1) * LL;
    // 5 descending streams, all tapped at m = j-1 (history regs give col j)
    float4 sVc  = *(const float4*)(vrow + 764);
    float4 sVn  = *(const float4*)(vrow + 760);
    float4 sTic = *(const float4*)(thiR + 764);
    float4 sTin = *(const float4*)(thiR + 760);
    float4 sAic = *(const float4*)(aiR + 764);
    float4 sAin = *(const float4*)(aiR + 760);
    float4 sTmc = *(const float4*)(thm + 764);
    float4 sTmn = *(const float4*)(thm + 760);
    float4 sAmc = *(const float4*)(am + 764);
    float4 sAmn = *(const float4*)(am + 760);
    float hTi = 0.f, hTm = 0.f, hAm = 0.f, hV = 0.f, hE = 0.f;
    float4 eb = {};
    const int kb = 64 * w + 2, ke = 64 * w + 832;
    const int kbp = kb + 64;  // producer (w+1) k-base
    int sW = ke % 3;          // k%3
    int sP1 = (ke + 1) % 3;   // (k+1)%3
    int sP2 = (ke + 2) % 3;   // (k+2)%3
    for (int k = ke; k >= kb; --k) {
      const int j = k - i;
      if (j >= 1 && j <= LL) {
        const int m = j - 1, c = m & 3;
        const float vcur = sel4(sVc, c);   // V[i][j]
        const float tic  = sel4(sTic, c);  // th0[i][j-1]
        const float aic  = sel4(sAic, c);  // a0[i][j-1]
        const float tmc  = sel4(sTmc, c);  // th0[i-1][j-1]
        const float amc  = sel4(sAmc, c);  // a0[i-1][j-1]
        float Vn1 = 0.f, Vn2 = 0.f, En1 = 0.f, En2 = 0.f;
        if (l == 63) {
          if (w < 11) {
            while (__hip_atomic_load(&Pb[w + 1], __ATOMIC_ACQUIRE,
                                     __HIP_MEMORY_SCOPE_WORKGROUP) > k + 1) {}
            Vn1 = Bv2[w * 768 + (k + 1 - kbp)];
            En1 = Be2[w * 768 + (k + 1 - kbp)];
            if (j < LL) {
              Vn2 = Bv2[w * 768 + (k + 2 - kbp)];
              En2 = Be2[w * 768 + (k + 2 - kbp)];
            }
          }
        } else {
          Vn1 = Vr2[sP1 * 772 + (i + 1)];
          En1 = Er[sP1 * 772 + (i + 1)];
          Vn2 = Vr2[sP2 * 772 + (i + 1)];
          En2 = Er[sP2 * 772 + (i + 1)];
        }
        float e;
        if (i == LL && j == LL) {
          e = 1.f;
        } else {
          e = 0.f;
          if (i < LL && j < LL) e += En2 * __expf(vcur - Vn2 + hTi);
          if (j < LL)           e += hE  * __expf(hAm + vcur - hV + hTm);
          if (i < LL)           e += En1 * __expf(aic + vcur - Vn1 + tic);
        }
        Vr2[sW * 772 + i] = vcur;
        Er[sW * 772 + i]  = e;
        if (l == 0 && w > 0) {
          Bv2[(w - 1) * 768 + (k - kb)] = vcur;
          Be2[(w - 1) * 768 + (k - kb)] = e;
          __hip_atomic_store(&Pb[w], k, __ATOMIC_RELEASE,
                             __HIP_MEMORY_SCOPE_WORKGROUP);
        }
        ins4(eb, c, e);
        if (c == 0) *(float4*)(erow + m) = eb;
        hTi = tic; hTm = tmc; hAm = amc; hV = vcur; hE = e;
        if (c == 0) {
          sVc = sVn; sTic = sTin; sAic = sAin; sTmc = sTmn; sAmc = sAmn;
          const int nb2 = (m - 8 > 0) ? (m - 8) : 0;
          sVn  = *(const float4*)(vrow + nb2);
          sTin = *(const float4*)(thiR + nb2);
          sAin = *(const float4*)(aiR + nb2);
          sTmn = *(const float4*)(thm + nb2);
          sAmn = *(const float4*)(am + nb2);
        }
      }
      { const int tmp = sP2; sP2 = sP1; sP1 = sW; sW = tmp; }
      asm volatile("" ::: "memory");
    }
  }
}

}  // namespace

extern "C" void kernel_launch(void* const* d_in, const int* in_sizes, int n_in,
                              void* d_out, int out_size, void* d_ws, size_t ws_size,
                              hipStream_t stream) {
  const float* hx = (const float*)d_in[0];
  const float* hy = (const float*)d_in[1];
  const float* Wm = (const float*)d_in[2];
  const float* bm = (const float*)d_in[3];
  const float* Wg = (const float*)d_in[4];
  const float* bg = (const float*)d_in[5];

  float* aln   = (float*)d_out;
  float* theta = aln + (size_t)BB * L2E;
  float* A     = theta + (size_t)BB * L2E;

  // phase 1 workspace (dead after logits): zx, zy, gx, gy
  float* zx = (float*)d_ws;
  float* zy = zx + (size_t)BB * LL * DD;
  float* gx = zy + (size_t)BB * LL * DD;
  float* gy = gx + (size_t)BB * LL * DD;
  // phase 2 workspace (reuses the region): V row-major
  float* Vst = (float*)d_ws;

  linear_kernel<<<dim3(DD / 64, (BB * LL) / 64, 4), 256, 0, stream>>>(
      hx, hy, Wm, bm, Wg, bg, zx, zy, gx, gy);
  logits_kernel<<<dim3(LL / 64, LL / 64, BB * 2), 256, 0, stream>>>(
      zx, zy, gx, gy, theta, A);

  const size_t SH = (size_t)(32 + 13088 + 8448) * sizeof(float);  // 86,272 B
  nw_fused<<<dim3(BB), 768, SH, stream>>>(theta, A, Vst, aln);
}

// Round 4
// 2412.927 us; speedup vs baseline: 3.2895x; 1.2223x over previous
//
#include <hip/hip_runtime.h>
#include <math.h>

namespace {

constexpr int BB = 8;
constexpr int LL = 768;
constexpr int DD = 512;
constexpr int L2E = LL * LL;
constexpr float NEGF = -1e9f;

__device__ __forceinline__ float softplus_f(float x) {
  return x > 0.f ? x + log1pf(expf(-x)) : log1pf(expf(x));
}
__device__ __forceinline__ float logsigmoid_f(float x) {
  return x > 0.f ? -log1pf(expf(-x)) : x - log1pf(expf(x));
}

__device__ __forceinline__ void ins4(float4& q, int c, float v) {
  if (c == 0) q.x = v;
  else if (c == 1) q.y = v;
  else if (c == 2) q.z = v;
  else q.w = v;
}

// diag-compact: diag s = r + c (0-based), element index doffc(s) + r - max(0,s-767)
__device__ __forceinline__ int doffc(int s) {
  return (s <= LL - 1) ? ((s * (s + 1)) >> 1)
                       : (L2E - (((2 * LL - 1 - s) * (2 * LL - s)) >> 1));
}
__device__ __forceinline__ int dIdxClamp(int s, int r) {
  s = s < 0 ? 0 : (s > 2 * LL - 2 ? 2 * LL - 2 : s);
  int idx = doffc(s) + r - (s > LL - 1 ? s - (LL - 1) : 0);
  return idx < 0 ? 0 : (idx >= L2E ? L2E - 1 : idx);
}

// -------- Kernel A: out[r][c] = sum_d X[r][d] * W[c][d] + bias[c] --------
__global__ __launch_bounds__(256) void linear_kernel(
    const float* __restrict__ hx, const float* __restrict__ hy,
    const float* __restrict__ Wm, const float* __restrict__ bm,
    const float* __restrict__ Wg, const float* __restrict__ bg,
    float* __restrict__ zx, float* __restrict__ zy,
    float* __restrict__ gx, float* __restrict__ gy) {
  constexpr int BK = 16;
  __shared__ float Xs[BK][64 + 1];
  __shared__ float Ws[BK][64 + 1];

  const int which = blockIdx.z;
  const float* Xin  = (which & 1) ? hy : hx;
  const float* W    = (which >= 2) ? Wg : Wm;
  const float* bias = (which >= 2) ? bg : bm;
  float* out = (which == 0) ? zx : (which == 1) ? zy : (which == 2) ? gx : gy;

  const int row0 = blockIdx.y * 64;
  const int col0 = blockIdx.x * 64;
  const int t  = threadIdx.x;
  const int tx = t & 15;
  const int ty = t >> 4;
  const int lrow = t >> 2;
  const int lseg = (t & 3) * 4;

  float acc[4][4] = {};
  for (int k0 = 0; k0 < DD; k0 += BK) {
    const float4 xv = *(const float4*)(Xin + (size_t)(row0 + lrow) * DD + k0 + lseg);
    const float4 wv = *(const float4*)(W   + (size_t)(col0 + lrow) * DD + k0 + lseg);
    Xs[lseg + 0][lrow] = xv.x; Xs[lseg + 1][lrow] = xv.y;
    Xs[lseg + 2][lrow] = xv.z; Xs[lseg + 3][lrow] = xv.w;
    Ws[lseg + 0][lrow] = wv.x; Ws[lseg + 1][lrow] = wv.y;
    Ws[lseg + 2][lrow] = wv.z; Ws[lseg + 3][lrow] = wv.w;
    __syncthreads();
#pragma unroll
    for (int kk = 0; kk < BK; ++kk) {
      float xr[4], wr[4];
#pragma unroll
      for (int a = 0; a < 4; ++a) xr[a] = Xs[kk][ty * 4 + a];
#pragma unroll
      for (int b = 0; b < 4; ++b) wr[b] = Ws[kk][tx * 4 + b];
#pragma unroll
      for (int a = 0; a < 4; ++a)
#pragma unroll
        for (int b = 0; b < 4; ++b) acc[a][b] += xr[a] * wr[b];
    }
    __syncthreads();
  }
#pragma unroll
  for (int a = 0; a < 4; ++a) {
    const int r = row0 + ty * 4 + a;
#pragma unroll
    for (int b2 = 0; b2 < 4; ++b2) {
      const int c = col0 + tx * 4 + b2;
      out[(size_t)r * DD + c] = acc[a][b2] + bias[c];
    }
  }
}

// -------- Kernel B: theta/A batched logits --------
__global__ __launch_bounds__(256) void logits_kernel(
    const float* __restrict__ zx, const float* __restrict__ zy,
    const float* __restrict__ gx, const float* __restrict__ gy,
    float* __restrict__ theta, float* __restrict__ Aout) {
  constexpr int BK = 16;
  __shared__ float Xs[BK][64 + 1];
  __shared__ float Ys[BK][64 + 1];

  const int bz = blockIdx.z;
  const int b = bz >> 1, w = bz & 1;
  const float* X = (w ? gx : zx) + (size_t)b * LL * DD;
  const float* Y = (w ? gy : zy) + (size_t)b * LL * DD;
  float* out = (w ? Aout : theta) + (size_t)b * L2E;

  const int row0 = blockIdx.y * 64;
  const int col0 = blockIdx.x * 64;
  const int t  = threadIdx.x;
  const int tx = t & 15;
  const int ty = t >> 4;
  const int lrow = t >> 2;
  const int lseg = (t & 3) * 4;

  float acc[4][4] = {};
  for (int k0 = 0; k0 < DD; k0 += BK) {
    const float4 xv = *(const float4*)(X + (size_t)(row0 + lrow) * DD + k0 + lseg);
    const float4 yv = *(const float4*)(Y + (size_t)(col0 + lrow) * DD + k0 + lseg);
    Xs[lseg + 0][lrow] = xv.x; Xs[lseg + 1][lrow] = xv.y;
    Xs[lseg + 2][lrow] = xv.z; Xs[lseg + 3][lrow] = xv.w;
    Ys[lseg + 0][lrow] = yv.x; Ys[lseg + 1][lrow] = yv.y;
    Ys[lseg + 2][lrow] = yv.z; Ys[lseg + 3][lrow] = yv.w;
    __syncthreads();
#pragma unroll
    for (int kk = 0; kk < BK; ++kk) {
      float xr[4], yr[4];
#pragma unroll
      for (int a = 0; a < 4; ++a) xr[a] = Xs[kk][ty * 4 + a];
#pragma unroll
      for (int b2 = 0; b2 < 4; ++b2) yr[b2] = Ys[kk][tx * 4 + b2];
#pragma unroll
      for (int a = 0; a < 4; ++a)
#pragma unroll
        for (int b2 = 0; b2 < 4; ++b2) acc[a][b2] += xr[a] * yr[b2];
    }
    __syncthreads();
  }
#pragma unroll
  for (int a = 0; a < 4; ++a) {
    const int r = row0 + ty * 4 + a;
#pragma unroll
    for (int b2 = 0; b2 < 4; ++b2) {
      const int c = col0 + tx * 4 + b2;
      const float v = acc[a][b2];
      out[(size_t)r * LL + c] = w ? logsigmoid_f(v) : softplus_f(v);
    }
  }
}

// -------- row-major -> diag-compact transpose for theta, A --------
__global__ __launch_bounds__(256) void row2diag(
    const float* __restrict__ theta, const float* __restrict__ A,
    float* __restrict__ thD, float* __restrict__ aD) {
  __shared__ float tile[64 * 66];
  const int z = blockIdx.z;  // b*2 + which
  const int b = z >> 1, which = z & 1;
  const float* in = (which ? A : theta) + (size_t)b * L2E;
  float* out = (which ? aD : thD) + (size_t)b * L2E;
  const int r0 = blockIdx.y * 64, c0 = blockIdx.x * 64;
  const int t = threadIdx.x, lane = t & 63, grp = t >> 6;
  for (int it = 0; it < 16; ++it) {
    const int rr = it * 4 + grp;
    tile[rr * 66 + lane] = in[(size_t)(r0 + rr) * LL + c0 + lane];
  }
  __syncthreads();
  for (int si = grp; si < 127; si += 4) {
    const int s = r0 + c0 + si;
    const int rlo = max(r0, s - c0 - 63);
    const int rhi = min(r0 + 63, s - c0);
    const int r = rlo + lane;
    if (r <= rhi)
      out[doffc(s) + r - max(0, s - (LL - 1))] = tile[(r - r0) * 66 + (s - r - c0)];
  }
}

// -------- Fused NW fwd+bwd: systolic waves + diag-compact coalesced streams --------
__global__ __launch_bounds__(768, 1) void nw_fused(
    const float* __restrict__ thD, const float* __restrict__ aD,
    float* __restrict__ Vd, float* __restrict__ aln) {
  extern __shared__ float sm[];
  int* Pf = (int*)sm;         // [12]
  int* Pb = (int*)sm + 16;    // [12]
  float* U = sm + 32;
  // forward layout
  float* VrF = U;             // 3 * 772
  float* Bv  = U + 2320;      // 11 * 832
  // backward layout (reuses U)
  float* Vr2 = U;             // 3 * 772
  float* Er  = U + 2320;      // 3 * 772
  float* Bv2 = U + 4640;      // 11 * 832
  float* Be2 = U + 13792;     // 11 * 832

  const int b = blockIdx.x;
  const float* thDb = thD + (size_t)b * L2E;
  const float* aDb  = aD + (size_t)b * L2E;
  float* Vob = Vd + (size_t)b * L2E;
  float* Eb_ = aln + (size_t)b * L2E;

  const int t = threadIdx.x;
  const int w = t >> 6, l = t & 63;
  const int i = t + 1;  // DP row 1..768

  if (t < 12) { Pf[t] = 0; Pb[t] = 0x7fffffff; }
  __syncthreads();

  const int kb = 64 * w + 2, ke = kb + 830;

  // ================= forward =================
  {
    const int kbp = kb - 64;  // producer (w-1) k-base
    float pT[8], pA[8];
#pragma unroll
    for (int u = 0; u < 8; ++u) {
      pT[u] = thDb[dIdxClamp(kb + u - 2, t)];
      pA[u] = aDb[dIdxClamp(kb + u - 2, t)];
    }
    float hv1 = NEGF, hVu = NEGF;
    for (int kg = kb; kg <= ke; kg += 8) {
#pragma unroll
      for (int u = 0; u < 8; ++u) {
        const int k = kg + u;
        const float thv = pT[u], av = pA[u];
        pT[u] = thDb[dIdxClamp(k + 6, t)];   // (k+8)-2
        pA[u] = aDb[dIdxClamp(k + 6, t)];
        if (k >= i + 1 && k <= i + 768) {
          float Vu;
          if (l == 0) {
            if (w == 0) {
              Vu = NEGF;
            } else {
              while (__hip_atomic_load(&Pf[w - 1], __ATOMIC_ACQUIRE,
                                       __HIP_MEMORY_SCOPE_WORKGROUP) < k - 1) {}
              Vu = Bv[(w - 1) * 832 + (k - 1 - kbp)];
            }
          } else {
            Vu = VrF[((k - 1) % 3) * 772 + t];  // neighbor row i-1
          }
          const float Vdg = (k == i + 1) ? ((i == 1) ? 0.f : NEGF) : hVu;
          const float lft = av + hv1, up = av + Vu;
          const float mx = fmaxf(Vdg, fmaxf(lft, up));
          const float v = thv + mx +
              __logf(__expf(Vdg - mx) + __expf(lft - mx) + __expf(up - mx));
          hv1 = v; hVu = Vu;
          VrF[(k % 3) * 772 + i] = v;
          const int s = k - 2;
          Vob[doffc(s) + t - (s > LL - 1 ? s - (LL - 1) : 0)] = v;
          if (l == 63 && w < 11) {
            Bv[w * 832 + (k - kb)] = v;
            __hip_atomic_store(&Pf[w], k, __ATOMIC_RELEASE,
                               __HIP_MEMORY_SCOPE_WORKGROUP);
          }
        }
        asm volatile("" ::: "memory");
      }
    }
  }
  __syncthreads();

  // ================= backward =================
  {
    const int kbp2 = kb + 64;  // producer (w+1) k-base
    float* erow = Eb_ + (size_t)t * LL;
    float sV[8], sT1[8], sT0[8], sA0[8], sT2[8], sA2[8];
#pragma unroll
    for (int u = 0; u < 8; ++u) {
      const int k = ke - u;
      sV[u]  = Vob[dIdxClamp(k - 2, t)];
      sT1[u] = thDb[dIdxClamp(k, t + 1)];
      sT0[u] = thDb[dIdxClamp(k - 1, t)];
      sA0[u] = aDb[dIdxClamp(k - 1, t)];
      sT2[u] = thDb[dIdxClamp(k - 1, t + 1)];
      sA2[u] = aDb[dIdxClamp(k - 1, t + 1)];
    }
    float hE = 0.f, hV = 0.f;
    float4 eb = {0.f, 0.f, 0.f, 0.f};
    for (int kg = ke; kg >= kb; kg -= 8) {
#pragma unroll
      for (int u = 0; u < 8; ++u) {
        const int k = kg - u;
        const float vcur = sV[u], t1 = sT1[u], t0 = sT0[u];
        const float a0v = sA0[u], t2 = sT2[u], a2v = sA2[u];
        sV[u]  = Vob[dIdxClamp(k - 10, t)];
        sT1[u] = thDb[dIdxClamp(k - 8, t + 1)];
        sT0[u] = thDb[dIdxClamp(k - 9, t)];
        sA0[u] = aDb[dIdxClamp(k - 9, t)];
        sT2[u] = thDb[dIdxClamp(k - 9, t + 1)];
        sA2[u] = aDb[dIdxClamp(k - 9, t + 1)];
        if (k >= i + 1 && k <= i + 768) {
          const int j = k - i;
          float Vn1 = 0.f, Vn2 = 0.f, En1 = 0.f, En2 = 0.f;
          if (l == 63) {
            if (w < 11) {
              while (__hip_atomic_load(&Pb[w + 1], __ATOMIC_ACQUIRE,
                                       __HIP_MEMORY_SCOPE_WORKGROUP) > k + 1) {}
              Vn1 = Bv2[w * 832 + (k + 1 - kbp2)];
              En1 = Be2[w * 832 + (k + 1 - kbp2)];
              Vn2 = Bv2[w * 832 + (k + 2 - kbp2)];
              En2 = Be2[w * 832 + (k + 2 - kbp2)];
            }
          } else {
            Vn1 = Vr2[((k + 1) % 3) * 772 + (i + 1)];
            En1 = Er[((k + 1) % 3) * 772 + (i + 1)];
            Vn2 = Vr2[((k + 2) % 3) * 772 + (i + 1)];
            En2 = Er[((k + 2) % 3) * 772 + (i + 1)];
          }
          float e;
          if (k == 2 * LL) {
            e = 1.f;  // cell (L, L)
          } else {
            e = 0.f;
            if (i < LL && j < LL) e += En2 * __expf(vcur - Vn2 + t1);
            if (j < LL)           e += hE  * __expf(a0v + vcur - hV + t0);
            if (i < LL)           e += En1 * __expf(a2v + vcur - Vn1 + t2);
          }
          Vr2[(k % 3) * 772 + i] = vcur;
          Er[(k % 3) * 772 + i]  = e;
          if (l == 0 && w > 0) {
            Bv2[(w - 1) * 832 + (k - kb)] = vcur;
            Be2[(w - 1) * 832 + (k - kb)] = e;
            __hip_atomic_store(&Pb[w], k, __ATOMIC_RELEASE,
                               __HIP_MEMORY_SCOPE_WORKGROUP);
          }
          const int m = j - 1, c = m & 3;
          ins4(eb, c, e);
          if (c == 0) *(float4*)(erow + m) = eb;
          hE = e; hV = vcur;
        }
        asm volatile("" ::: "memory");
      }
    }
  }
}

}  // namespace

extern "C" void kernel_launch(void* const* d_in, const int* in_sizes, int n_in,
                              void* d_out, int out_size, void* d_ws, size_t ws_size,
                              hipStream_t stream) {
  const float* hx = (const float*)d_in[0];
  const float* hy = (const float*)d_in[1];
  const float* Wm = (const float*)d_in[2];
  const float* bm = (const float*)d_in[3];
  const float* Wg = (const float*)d_in[4];
  const float* bg = (const float*)d_in[5];

  float* aln   = (float*)d_out;
  float* theta = aln + (size_t)BB * L2E;
  float* A     = theta + (size_t)BB * L2E;

  // phase-2 workspace: diag-compact theta/A/V (written after phase 1 is dead)
  float* thD = (float*)d_ws;
  float* aD  = thD + (size_t)BB * L2E;
  float* Vd  = aD + (size_t)BB * L2E;
  // phase-1 workspace aliases the same region (dead after logits)
  float* zx = (float*)d_ws;
  float* zy = zx + (size_t)BB * LL * DD;
  float* gx = zy + (size_t)BB * LL * DD;
  float* gy = gx + (size_t)BB * LL * DD;

  linear_kernel<<<dim3(DD / 64, (BB * LL) / 64, 4), 256, 0, stream>>>(
      hx, hy, Wm, bm, Wg, bg, zx, zy, gx, gy);
  logits_kernel<<<dim3(LL / 64, LL / 64, BB * 2), 256, 0, stream>>>(
      zx, zy, gx, gy, theta, A);
  row2diag<<<dim3(LL / 64, LL / 64, BB * 2), 256, 0, stream>>>(theta, A, thD, aD);

  const size_t SH = (size_t)(32 + 2320 + 2320 + 9152 + 9152) * sizeof(float);  // 91,904 B
  nw_fused<<<dim3(BB), 768, SH, stream>>>(thD, aD, Vd, aln);
}

// Round 6
// 2263.019 us; speedup vs baseline: 3.5074x; 1.0662x over previous
//
#include <hip/hip_runtime.h>
#include <math.h>

namespace {

constexpr int BB = 8;
constexpr int LL = 768;
constexpr int DD = 512;
constexpr int L2E = LL * LL;
constexpr float NEGF = -1e9f;

__device__ __forceinline__ float softplus_f(float x) {
  return x > 0.f ? x + log1pf(expf(-x)) : log1pf(expf(x));
}
__device__ __forceinline__ float logsigmoid_f(float x) {
  return x > 0.f ? -log1pf(expf(-x)) : x - log1pf(expf(x));
}

// diag-compact: diag s = r + c (0-based), element index Jext(s, r)
__device__ __forceinline__ int doffc(int s) {
  return (s <= LL - 1) ? ((s * (s + 1)) >> 1)
                       : (L2E - (((2 * LL - 1 - s) * (2 * LL - s)) >> 1));
}
__device__ __forceinline__ int Jext(int s, int r) {
  return doffc(s) + r - ((s > LL - 1) ? (s - (LL - 1)) : 0);
}
// index delta when s -> s+1 (same row)
__device__ __forceinline__ int dJa(int s) { return (s <= LL - 2) ? s + 1 : 2 * LL - 2 - s; }
// index delta when s -> s-1 (same row)
__device__ __forceinline__ int dJd(int s) { return (s <= LL - 1) ? -s : s - (2 * LL - 1); }

// -------- Kernel A: out[r][c] = sum_d X[r][d] * W[c][d] + bias[c] --------
__global__ __launch_bounds__(256) void linear_kernel(
    const float* __restrict__ hx, const float* __restrict__ hy,
    const float* __restrict__ Wm, const float* __restrict__ bm,
    const float* __restrict__ Wg, const float* __restrict__ bg,
    float* __restrict__ zx, float* __restrict__ zy,
    float* __restrict__ gx, float* __restrict__ gy) {
  constexpr int BK = 16;
  __shared__ float Xs[BK][64 + 1];
  __shared__ float Ws[BK][64 + 1];

  const int which = blockIdx.z;
  const float* Xin  = (which & 1) ? hy : hx;
  const float* W    = (which >= 2) ? Wg : Wm;
  const float* bias = (which >= 2) ? bg : bm;
  float* out = (which == 0) ? zx : (which == 1) ? zy : (which == 2) ? gx : gy;

  const int row0 = blockIdx.y * 64;
  const int col0 = blockIdx.x * 64;
  const int t  = threadIdx.x;
  const int tx = t & 15;
  const int ty = t >> 4;
  const int lrow = t >> 2;
  const int lseg = (t & 3) * 4;

  float acc[4][4] = {};
  for (int k0 = 0; k0 < DD; k0 += BK) {
    const float4 xv = *(const float4*)(Xin + (size_t)(row0 + lrow) * DD + k0 + lseg);
    const float4 wv = *(const float4*)(W   + (size_t)(col0 + lrow) * DD + k0 + lseg);
    Xs[lseg + 0][lrow] = xv.x; Xs[lseg + 1][lrow] = xv.y;
    Xs[lseg + 2][lrow] = xv.z; Xs[lseg + 3][lrow] = xv.w;
    Ws[lseg + 0][lrow] = wv.x; Ws[lseg + 1][lrow] = wv.y;
    Ws[lseg + 2][lrow] = wv.z; Ws[lseg + 3][lrow] = wv.w;
    __syncthreads();
#pragma unroll
    for (int kk = 0; kk < BK; ++kk) {
      float xr[4], wr[4];
#pragma unroll
      for (int a = 0; a < 4; ++a) xr[a] = Xs[kk][ty * 4 + a];
#pragma unroll
      for (int b = 0; b < 4; ++b) wr[b] = Ws[kk][tx * 4 + b];
#pragma unroll
      for (int a = 0; a < 4; ++a)
#pragma unroll
        for (int b = 0; b < 4; ++b) acc[a][b] += xr[a] * wr[b];
    }
    __syncthreads();
  }
#pragma unroll
  for (int a = 0; a < 4; ++a) {
    const int r = row0 + ty * 4 + a;
#pragma unroll
    for (int b2 = 0; b2 < 4; ++b2) {
      const int c = col0 + tx * 4 + b2;
      out[(size_t)r * DD + c] = acc[a][b2] + bias[c];
    }
  }
}

// -------- Kernel B: theta/A batched logits --------
__global__ __launch_bounds__(256) void logits_kernel(
    const float* __restrict__ zx, const float* __restrict__ zy,
    const float* __restrict__ gx, const float* __restrict__ gy,
    float* __restrict__ theta, float* __restrict__ Aout) {
  constexpr int BK = 16;
  __shared__ float Xs[BK][64 + 1];
  __shared__ float Ys[BK][64 + 1];

  const int bz = blockIdx.z;
  const int b = bz >> 1, w = bz & 1;
  const float* X = (w ? gx : zx) + (size_t)b * LL * DD;
  const float* Y = (w ? gy : zy) + (size_t)b * LL * DD;
  float* out = (w ? Aout : theta) + (size_t)b * L2E;

  const int row0 = blockIdx.y * 64;
  const int col0 = blockIdx.x * 64;
  const int t  = threadIdx.x;
  const int tx = t & 15;
  const int ty = t >> 4;
  const int lrow = t >> 2;
  const int lseg = (t & 3) * 4;

  float acc[4][4] = {};
  for (int k0 = 0; k0 < DD; k0 += BK) {
    const float4 xv = *(const float4*)(X + (size_t)(row0 + lrow) * DD + k0 + lseg);
    const float4 yv = *(const float4*)(Y + (size_t)(col0 + lrow) * DD + k0 + lseg);
    Xs[lseg + 0][lrow] = xv.x; Xs[lseg + 1][lrow] = xv.y;
    Xs[lseg + 2][lrow] = xv.z; Xs[lseg + 3][lrow] = xv.w;
    Ys[lseg + 0][lrow] = yv.x; Ys[lseg + 1][lrow] = yv.y;
    Ys[lseg + 2][lrow] = yv.z; Ys[lseg + 3][lrow] = yv.w;
    __syncthreads();
#pragma unroll
    for (int kk = 0; kk < BK; ++kk) {
      float xr[4], yr[4];
#pragma unroll
      for (int a = 0; a < 4; ++a) xr[a] = Xs[kk][ty * 4 + a];
#pragma unroll
      for (int b2 = 0; b2 < 4; ++b2) yr[b2] = Ys[kk][tx * 4 + b2];
#pragma unroll
      for (int a = 0; a < 4; ++a)
#pragma unroll
        for (int b2 = 0; b2 < 4; ++b2) acc[a][b2] += xr[a] * yr[b2];
    }
    __syncthreads();
  }
#pragma unroll
  for (int a = 0; a < 4; ++a) {
    const int r = row0 + ty * 4 + a;
#pragma unroll
    for (int b2 = 0; b2 < 4; ++b2) {
      const int c = col0 + tx * 4 + b2;
      const float v = acc[a][b2];
      out[(size_t)r * LL + c] = w ? logsigmoid_f(v) : softplus_f(v);
    }
  }
}

// -------- row-major -> diag-compact transpose for theta, A --------
__global__ __launch_bounds__(256) void row2diag(
    const float* __restrict__ theta, const float* __restrict__ A,
    float* __restrict__ thD, float* __restrict__ aD) {
  __shared__ float tile[64 * 66];
  const int z = blockIdx.z;  // b*2 + which
  const int b = z >> 1, which = z & 1;
  const float* in = (which ? A : theta) + (size_t)b * L2E;
  float* out = (which ? aD : thD) + (size_t)b * L2E;
  const int r0 = blockIdx.y * 64, c0 = blockIdx.x * 64;
  const int t = threadIdx.x, lane = t & 63, grp = t >> 6;
  for (int it = 0; it < 16; ++it) {
    const int rr = it * 4 + grp;
    tile[rr * 66 + lane] = in[(size_t)(r0 + rr) * LL + c0 + lane];
  }
  __syncthreads();
  for (int si = grp; si < 127; si += 4) {
    const int s = r0 + c0 + si;
    const int rlo = max(r0, s - c0 - 63);
    const int rhi = min(r0 + 63, s - c0);
    const int r = rlo + lane;
    if (r <= rhi)
      out[doffc(s) + r - max(0, s - (LL - 1))] = tile[(r - r0) * 66 + (s - r - c0)];
  }
}

// -------- diag-compact -> row-major (aln) --------
__global__ __launch_bounds__(256) void diag2row(
    const float* __restrict__ Ed, float* __restrict__ aln) {
  __shared__ float tile[64 * 66];
  const int b = blockIdx.z;
  const int r0 = blockIdx.y * 64;
  const int c0 = blockIdx.x * 64;
  const float* E = Ed + (size_t)b * L2E;
  float* out = aln + (size_t)b * L2E;
  const int t = threadIdx.x;
  const int lane = t & 63;
  const int grp = t >> 6;  // 0..3
  for (int si = grp; si < 127; si += 4) {
    const int s = r0 + c0 + si;
    const int rlo = max(r0, s - c0 - 63);
    const int rhi = min(r0 + 63, s - c0);
    const int r = rlo + lane;
    if (r <= rhi) {
      tile[(r - r0) * 66 + (s - r - c0)] = E[doffc(s) + r - max(0, s - (LL - 1))];
    }
  }
  __syncthreads();
  for (int it = 0; it < 16; ++it) {
    const int rr = it * 4 + grp;
    out[(size_t)(r0 + rr) * LL + c0 + lane] = tile[rr * 66 + lane];
  }
}

// -------- Fused NW fwd+bwd: 4 rows/lane, 3 waves/batch, systolic pipeline --------
// Lane t owns rows 4t+1..4t+4 (1-based). Per step k, lane computes 4 cells on
// anti-diagonal k. 3 of 4 neighbor deps are register history; row 4t comes via
// a 4-slot LDS ring from lane t-1 (static slot = k&3, compile-time in the
// 8-unrolled body). Wave boundaries exchange through full-history LDS buffers
// with acquire/release flags, polled once per 8-step group.
// E overwrites V in-place (diag s=k-2 written after last V read at s=k-6).
// NOTE: Pf/Pb sized 4 — backward publishes Pb[w] for w up to 2 (R5 bug: Pb[2]
// was OOB into RingVf, consumers read garbage progress -> NaN).
__global__ __launch_bounds__(192, 1) void nw_fused(
    const float* __restrict__ thD, const float* __restrict__ aD,
    float* __restrict__ VEd) {
  __shared__ int Pf[4], Pb[4];
  __shared__ float RingVf[4][256];
  __shared__ float RingVb[4][256];
  __shared__ float RingEb[4][256];
  __shared__ float BvF[2][1024];
  __shared__ float Bv2[2][1024];
  __shared__ float Be2[2][1024];

  const int b = blockIdx.x;
  const float* th = thD + (size_t)b * L2E;
  const float* aa = aD + (size_t)b * L2E;
  float* V = VEd + (size_t)b * L2E;

  const int t = threadIdx.x;
  const int w = t >> 6, l = t & 63;
  const int rowb = 4 * t;           // 0-based row of first owned cell - 1
  const int kb = 256 * w + 2;
  const int ke = kb + 1023;

  if (t < 4) { Pf[t] = 0; Pb[t] = 0x7fffffff; }
  __syncthreads();

  // ================= forward =================
  {
    float pth[4][4], pa[4][4];
    int sL = kb - 2, iL = Jext(sL, rowb);
#pragma unroll
    for (int du = 0; du < 4; ++du) {
      const int slot = (2 + du) & 3;
#pragma unroll
      for (int r = 0; r < 4; ++r) { pth[slot][r] = th[iL + r]; pa[slot][r] = aa[iL + r]; }
      iL += dJa(sL); ++sL;
    }
    int sS = kb - 2, iS = Jext(sS, rowb);
    float p1[4], p2[4];
#pragma unroll
    for (int r = 0; r < 4; ++r) { p1[r] = NEGF; p2[r] = NEGF; }
    float rvh = NEGF;
    float bv[8], pub[8];
    const int rdT = (t == 0) ? 0 : (t - 1);

    for (int kg = kb; kg < kb + 1024; kg += 8) {
      if (l == 0 && w > 0 && kg < kb + 768) {
        const int need = min(kg + 6, kb + 766);
        while (__hip_atomic_load(&Pf[w - 1], __ATOMIC_ACQUIRE,
                                 __HIP_MEMORY_SCOPE_WORKGROUP) < need) {}
        const int boff = kg - kb + 255;
#pragma unroll
        for (int u = 0; u < 8; ++u) bv[u] = BvF[w - 1][boff + u];
      }
#pragma unroll
      for (int u = 0; u < 8; ++u) {
        const int k = kg + u;
        const int su = (2 + u) & 3;  // k & 3
        const int ru = (1 + u) & 3;  // (k-1) & 3
        float rv = RingVf[ru][rdT];
        if (l == 0) rv = (w == 0) ? NEGF : bv[u];
        float rdg = rvh;
        if (l == 0 && w == 0) rdg = (k == 2) ? 0.f : NEGF;
        const int d = k - rowb - 2;
        float vv[4];
#pragma unroll
        for (int r = 0; r < 4; ++r) {
          const float Vl = p1[r];
          const float Vu = (r == 0) ? rv : p1[r - 1];
          const float Vg = (r == 0) ? rdg : p2[r - 1];
          const float av = pa[su][r], tv = pth[su][r];
          const float lft = av + Vl, up = av + Vu;
          const float mx = fmaxf(Vg, fmaxf(lft, up));
          const float val = tv + mx +
              __logf(__expf(Vg - mx) + __expf(lft - mx) + __expf(up - mx));
          vv[r] = ((unsigned)(d - r) <= 767u) ? val : NEGF;
        }
        // refill slot su for step k+4 (s = k+2)
#pragma unroll
        for (int r = 0; r < 4; ++r) { pth[su][r] = th[iL + r]; pa[su][r] = aa[iL + r]; }
        iL += dJa(sL); ++sL;
        // V store (s = k-2), masked per component
#pragma unroll
        for (int r = 0; r < 4; ++r)
          if ((unsigned)(d - r) <= 767u) V[iS + r] = vv[r];
        iS += dJa(sS); ++sS;
        RingVf[su][t] = vv[3];
        pub[u] = vv[3];
        rvh = rv;
#pragma unroll
        for (int r = 0; r < 4; ++r) { p2[r] = p1[r]; p1[r] = vv[r]; }
        asm volatile("" ::: "memory");
      }
      if (l == 63 && w < 2) {
        const int boff = kg - kb;
#pragma unroll
        for (int u = 0; u < 8; ++u) BvF[w][boff + u] = pub[u];
        __hip_atomic_store(&Pf[w], kg + 7, __ATOMIC_RELEASE,
                           __HIP_MEMORY_SCOPE_WORKGROUP);
      }
    }
  }
  __syncthreads();

  // ================= backward =================
  {
    float sVv[4][4];                 // V at s=k-2, rows rowb..rowb+3
    float sK[4][4];                  // th at s=k,   rows rowb+1..rowb+4
    float sK1t[4][5], sK1a[4][5];    // th/A at s=k-1, rows rowb..rowb+4
    int sV_ = ke - 2, iV = Jext(sV_, rowb);
    int sKc = ke,     iK = Jext(sKc, rowb);
    int sK1 = ke - 1, iK1 = Jext(sK1, rowb);
#pragma unroll
    for (int du = 0; du < 4; ++du) {
      const int slot = (1 - du) & 3;
#pragma unroll
      for (int r = 0; r < 4; ++r) sVv[slot][r] = V[iV + r];
#pragma unroll
      for (int r = 0; r < 4; ++r) sK[slot][r] = th[iK + 1 + r];
#pragma unroll
      for (int r = 0; r < 5; ++r) { sK1t[slot][r] = th[iK1 + r]; sK1a[slot][r] = aa[iK1 + r]; }
      iV += dJd(sV_); --sV_;
      iK += dJd(sKc); --sKc;
      iK1 += dJd(sK1); --sK1;
    }
    int sE = ke - 2, iE = Jext(sE, rowb);
    float N1v[4], N1e[4], N2v[4], N2e[4], hV[4], hE[4];
#pragma unroll
    for (int r = 0; r < 4; ++r) {
      N1v[r] = 0.f; N1e[r] = 0.f; N2v[r] = 0.f; N2e[r] = 0.f; hV[r] = 0.f; hE[r] = 0.f;
    }
    float bvn[10], ben[10];
    const int kbP = kb + 256;

    for (int kg = ke; kg > ke - 1024; kg -= 8) {
      if (l == 63 && w < 2 && kg >= kb + 255) {
        const int need = max(kg - 6, kbP);
        while (__hip_atomic_load(&Pb[w + 1], __ATOMIC_ACQUIRE,
                                 __HIP_MEMORY_SCOPE_WORKGROUP) > need) {}
#pragma unroll
        for (int m = 0; m < 10; ++m) {
          const int off = max(kg + 2 - m - kbP, 0);
          bvn[m] = Bv2[w][off];
          ben[m] = Be2[w][off];
        }
      }
      float pubV[8], pubE[8];
#pragma unroll
      for (int u = 0; u < 8; ++u) {
        const int k = kg - u;
        const int su = (1 - u) & 3;   // k & 3
        const int pu = (2 - u) & 3;   // (k+1) & 3
        // fill N1[3] (row 4t+5 @ k+1) from ring written last iteration / chunk
        {
          float nv3 = RingVb[pu][t + 1];
          float ne3 = RingEb[pu][t + 1];
          if (l == 63 && w < 2) { nv3 = bvn[u + 1]; ne3 = ben[u + 1]; }
          N1v[3] = nv3; N1e[3] = ne3;
        }
        const int d = k - rowb - 2;
        float e[4], vc[4];
#pragma unroll
        for (int r = 0; r < 4; ++r) {
          vc[r] = sVv[su][r];
          const bool ok  = (unsigned)(d - r) <= 767u;
          const bool jlt = (d - r) < 767;       // j < 768
          const bool ilt = (rowb + r) < 767;    // i < 768
          float acc = 0.f;
          if (ilt && jlt) acc += N2e[r] * __expf(vc[r] - N2v[r] + sK[su][r]);
          if (jlt)        acc += hE[r] * __expf(sK1a[su][r] + vc[r] - hV[r] + sK1t[su][r]);
          if (ilt)        acc += N1e[r] * __expf(sK1a[su][r + 1] + vc[r] - N1v[r] + sK1t[su][r + 1]);
          e[r] = ok ? acc : 0.f;
        }
        if (k == 2 * LL && t == 191) e[3] = 1.f;
        // refills for step k-4
#pragma unroll
        for (int r = 0; r < 4; ++r) sVv[su][r] = V[iV + r];
#pragma unroll
        for (int r = 0; r < 4; ++r) sK[su][r] = th[iK + 1 + r];
#pragma unroll
        for (int r = 0; r < 5; ++r) { sK1t[su][r] = th[iK1 + r]; sK1a[su][r] = aa[iK1 + r]; }
        iV += dJd(sV_); --sV_;
        iK += dJd(sKc); --sKc;
        iK1 += dJd(sK1); --sK1;
        // E store (s = k-2), masked; overwrites V (safe: V[s] last read at s+6)
#pragma unroll
        for (int r = 0; r < 4; ++r)
          if ((unsigned)(d - r) <= 767u) V[iE + r] = e[r];
        iE += dJd(sE); --sE;
        // ring publish of first-row values (read by lane t-1 next iteration)
        RingVb[su][t] = vc[0];
        RingEb[su][t] = e[0];
        pubV[u] = vc[0]; pubE[u] = e[0];
        // rotate histories
#pragma unroll
        for (int r = 0; r < 4; ++r) { N2v[r] = N1v[r]; N2e[r] = N1e[r]; }
        N1v[0] = vc[1]; N1e[0] = e[1];
        N1v[1] = vc[2]; N1e[1] = e[2];
        N1v[2] = vc[3]; N1e[2] = e[3];
#pragma unroll
        for (int r = 0; r < 4; ++r) { hV[r] = vc[r]; hE[r] = e[r]; }
        asm volatile("" ::: "memory");
      }
      if (l == 0 && w > 0) {
        const int boff = kg - kb;
#pragma unroll
        for (int u = 0; u < 8; ++u) {
          Bv2[w - 1][boff - u] = pubV[u];
          Be2[w - 1][boff - u] = pubE[u];
        }
        __hip_atomic_store(&Pb[w], kg - 7, __ATOMIC_RELEASE,
                           __HIP_MEMORY_SCOPE_WORKGROUP);
      }
    }
  }
}

}  // namespace

extern "C" void kernel_launch(void* const* d_in, const int* in_sizes, int n_in,
                              void* d_out, int out_size, void* d_ws, size_t ws_size,
                              hipStream_t stream) {
  const float* hx = (const float*)d_in[0];
  const float* hy = (const float*)d_in[1];
  const float* Wm = (const float*)d_in[2];
  const float* bm = (const float*)d_in[3];
  const float* Wg = (const float*)d_in[4];
  const float* bg = (const float*)d_in[5];

  float* aln   = (float*)d_out;
  float* theta = aln + (size_t)BB * L2E;
  float* A     = theta + (size_t)BB * L2E;

  // phase-2 workspace: diag-compact theta/A and V (E overwrites V in place)
  float* thD = (float*)d_ws;
  float* aD  = thD + (size_t)BB * L2E;
  float* VEd = aD + (size_t)BB * L2E;
  // phase-1 workspace aliases the same region (dead after logits)
  float* zx = (float*)d_ws;
  float* zy = zx + (size_t)BB * LL * DD;
  float* gx = zy + (size_t)BB * LL * DD;
  float* gy = gx + (size_t)BB * LL * DD;

  linear_kernel<<<dim3(DD / 64, (BB * LL) / 64, 4), 256, 0, stream>>>(
      hx, hy, Wm, bm, Wg, bg, zx, zy, gx, gy);
  logits_kernel<<<dim3(LL / 64, LL / 64, BB * 2), 256, 0, stream>>>(
      zx, zy, gx, gy, theta, A);
  row2diag<<<dim3(LL / 64, LL / 64, BB * 2), 256, 0, stream>>>(theta, A, thD, aD);

  nw_fused<<<dim3(BB), 192, 0, stream>>>(thD, aD, VEd);

  diag2row<<<dim3(LL / 64, LL / 64, BB), 256, 0, stream>>>(VEd, aln);
}